// Round 2
// baseline (291.239 us; speedup 1.0000x reference)
//
#include <hip/hip_runtime.h>

#define T_SEQ 512
#define BATCH 4096
#define D_IN  5
#define H     15
#define G4    60   // 4*H
#define OUTN  25

// ---------- helpers ----------
__device__ __forceinline__ float fast_exp2(float x) {
#if __has_builtin(__builtin_amdgcn_exp2f)
  return __builtin_amdgcn_exp2f(x);
#else
  return exp2f(x);
#endif
}

__device__ __forceinline__ float fast_rcp(float x) {
#if __has_builtin(__builtin_amdgcn_rcpf)
  return __builtin_amdgcn_rcpf(x);
#else
  return 1.0f / x;
#endif
}

__device__ __forceinline__ float rl(float v, int lane) {
  return __int_as_float(__builtin_amdgcn_readlane(__float_as_int(v), lane));
}

// broadcast quad-lane K (0..3) to all 4 lanes of each quad via DPP quad_perm
template <int K>
__device__ __forceinline__ float qbcast(float v) {
  return __int_as_float(__builtin_amdgcn_update_dpp(
      0, __float_as_int(v), K * 0x55, 0xF, 0xF, true));
}

// ---------- kernel A: xw0[t][g] = x[t,B-1,:]·w_ih0[g,:] + b_ih0[g] + b_hh0[g] ----------
__global__ void precompute_xw0(const float* __restrict__ x,
                               const float* __restrict__ w_ih0,
                               const float* __restrict__ b_ih0,
                               const float* __restrict__ b_hh0,
                               float* __restrict__ xw0) {
  int idx = blockIdx.x * blockDim.x + threadIdx.x;
  if (idx >= T_SEQ * G4) return;
  int t = idx / G4;
  int g = idx - t * G4;
  const float* xp = x + ((size_t)t * BATCH + (BATCH - 1)) * D_IN;
  float a = b_ih0[g] + b_hh0[g];
#pragma unroll
  for (int d = 0; d < D_IN; ++d) a = fmaf(xp[d], w_ih0[g * D_IN + d], a);
  xw0[idx] = a;
}

// ---------- kernel B: serial 2-layer LSTM + linear, one wave ----------
// lane = 4*unit + gate_type ; gate_type in {0:i, 1:f, 2:g(tanh), 3:o}
__global__ void __launch_bounds__(64, 1)
lstm_serial(const float* __restrict__ xw0,
            const float* __restrict__ w_hh0,
            const float* __restrict__ w_ih1,
            const float* __restrict__ w_hh1,
            const float* __restrict__ b_ih1,
            const float* __restrict__ b_hh1,
            const float* __restrict__ w_lin,
            const float* __restrict__ b_lin,
            float* __restrict__ out) {
  const int lane = threadIdx.x;
  const int ty = lane & 3;
  const int j  = lane >> 2;                  // unit 0..15 (15 = idle quad)
  const int g  = (j < H) ? (ty * H + j) : 0; // PyTorch gate row (i,f,g,o blocks)

  // per-lane weight rows (registers)
  float w0[H], wi1[H], wh1[H];
#pragma unroll
  for (int k = 0; k < H; ++k) {
    w0[k]  = w_hh0[g * H + k];
    wi1[k] = w_ih1[g * H + k];
    wh1[k] = w_hh1[g * H + k];
  }
  const float bias1 = b_ih1[g] + b_hh1[g];

  // linear weights on lanes 0..24
  float wl[H];
  {
    int o = (lane < OUTN) ? lane : 0;
#pragma unroll
    for (int k = 0; k < H; ++k) wl[k] = w_lin[o * H + k];
  }
  const float bl = b_lin[(lane < OUTN) ? lane : 0];

  // activation constants: sigmoid(x)=rcp(1+2^(-x*log2e)); tanh(x)=2*sigmoid(2x)-1
  const bool  isT  = (ty == 2);
  const float expc = isT ? -2.8853900817779268f : -1.4426950408889634f;
  const float sc   = isT ? 2.0f : 1.0f;
  const float off  = isT ? -1.0f : 0.0f;
  const float TANH_C = -2.8853900817779268f;

  float c0 = 0.0f, c1 = 0.0f;
  float sh0[H], sh1[H];
#pragma unroll
  for (int k = 0; k < H; ++k) { sh0[k] = 0.0f; sh1[k] = 0.0f; }

  // 2-deep xw prefetch pipeline
  float xw_cur = xw0[g];                     // t = 0
  float xw_n1  = xw0[1 * G4 + g];            // t = 1

  for (int t = 0; t < T_SEQ; ++t) {
    // prefetch t+2 (L2-resident; 2 steps of cover >> load latency)
    int tn = (t + 2 < T_SEQ) ? (t + 2) : 0;
    float xw_n2 = xw0[tn * G4 + g];

    // ---- hoisted: layer-1 recurrent half-dot (depends only on sh1[t-1]) ----
    float u3 = 0.0f, u4 = 0.0f, u5 = 0.0f;
#pragma unroll
    for (int k = 0; k < 5; ++k)   u3 = fmaf(wh1[k], sh1[k], u3);
#pragma unroll
    for (int k = 5; k < 10; ++k)  u4 = fmaf(wh1[k], sh1[k], u4);
#pragma unroll
    for (int k = 10; k < 15; ++k) u5 = fmaf(wh1[k], sh1[k], u5);

    // ---- layer 0: recurrent dot (15 FMA, 3 chains) ----
    float a0 = xw_cur, a1 = 0.0f, a2 = 0.0f;
#pragma unroll
    for (int k = 0; k < 5; ++k)   a0 = fmaf(w0[k], sh0[k], a0);
#pragma unroll
    for (int k = 5; k < 10; ++k)  a1 = fmaf(w0[k], sh0[k], a1);
#pragma unroll
    for (int k = 10; k < 15; ++k) a2 = fmaf(w0[k], sh0[k], a2);
    float a = a0 + (a1 + a2);

    // fused sigmoid/tanh
    float e = fast_exp2(a * expc);
    float s = fast_rcp(1.0f + e);
    float v = fmaf(s, sc, off);

    // gather i,f,g,o inside the quad (DPP, no LDS)
    float vi = qbcast<0>(v), vf = qbcast<1>(v), vg = qbcast<2>(v), vo = qbcast<3>(v);
    c0 = fmaf(vf, c0, vi * vg);
    float ec = fast_exp2(c0 * TANH_C);
    float th = fmaf(fast_rcp(1.0f + ec), 2.0f, -1.0f);
    float h0v = vo * th;

    // broadcast h0 to wave-uniform scalars
#pragma unroll
    for (int k = 0; k < H; ++k) sh0[k] = rl(h0v, 4 * k);

    // ---- layer 1: input half-dot (15 FMA, 3 chains) + combine ----
    float u0 = bias1, u1 = 0.0f, u2 = 0.0f;
#pragma unroll
    for (int k = 0; k < 5; ++k)   u0 = fmaf(wi1[k], sh0[k], u0);
#pragma unroll
    for (int k = 5; k < 10; ++k)  u1 = fmaf(wi1[k], sh0[k], u1);
#pragma unroll
    for (int k = 10; k < 15; ++k) u2 = fmaf(wi1[k], sh0[k], u2);
    float b = ((u0 + u1) + (u2 + u3)) + (u4 + u5);

    float eb = fast_exp2(b * expc);
    float sb = fast_rcp(1.0f + eb);
    float vb = fmaf(sb, sc, off);

    float qi = qbcast<0>(vb), qf = qbcast<1>(vb), qg = qbcast<2>(vb), qo = qbcast<3>(vb);
    c1 = fmaf(qf, c1, qi * qg);
    float ec1 = fast_exp2(c1 * TANH_C);
    float th1 = fmaf(fast_rcp(1.0f + ec1), 2.0f, -1.0f);
    float h1v = qo * th1;

#pragma unroll
    for (int k = 0; k < H; ++k) sh1[k] = rl(h1v, 4 * k);

    // ---- linear 15->25 on lanes 0..24 ----
    float o0 = bl, o1 = 0.0f, o2 = 0.0f;
#pragma unroll
    for (int k = 0; k < 5; ++k)   o0 = fmaf(wl[k], sh1[k], o0);
#pragma unroll
    for (int k = 5; k < 10; ++k)  o1 = fmaf(wl[k], sh1[k], o1);
#pragma unroll
    for (int k = 10; k < 15; ++k) o2 = fmaf(wl[k], sh1[k], o2);
    if (lane < OUTN) out[t * OUTN + lane] = o0 + (o1 + o2);

    // rotate prefetch pipeline
    xw_cur = xw_n1;
    xw_n1  = xw_n2;
  }
}

// ---------- launch ----------
extern "C" void kernel_launch(void* const* d_in, const int* in_sizes, int n_in,
                              void* d_out, int out_size, void* d_ws, size_t ws_size,
                              hipStream_t stream) {
  const float* x     = (const float*)d_in[0];
  const float* w_ih0 = (const float*)d_in[1];
  const float* w_hh0 = (const float*)d_in[2];
  const float* b_ih0 = (const float*)d_in[3];
  const float* b_hh0 = (const float*)d_in[4];
  const float* w_ih1 = (const float*)d_in[5];
  const float* w_hh1 = (const float*)d_in[6];
  const float* b_ih1 = (const float*)d_in[7];
  const float* b_hh1 = (const float*)d_in[8];
  const float* w_lin = (const float*)d_in[9];
  const float* b_lin = (const float*)d_in[10];
  float* out = (float*)d_out;
  float* xw0 = (float*)d_ws;  // 512*60*4 = 122880 B

  precompute_xw0<<<dim3((T_SEQ * G4 + 255) / 256), dim3(256), 0, stream>>>(
      x, w_ih0, b_ih0, b_hh0, xw0);
  lstm_serial<<<dim3(1), dim3(64), 0, stream>>>(
      xw0, w_hh0, w_ih1, w_hh1, b_ih1, b_hh1, w_lin, b_lin, out);
}

// Round 8
// 236.931 us; speedup vs baseline: 1.2292x; 1.2292x over previous
//
#include <hip/hip_runtime.h>

#define T_SEQ 512
#define BATCH 4096
#define D_IN  5
#define H     15
#define G4    60   // 4*H
#define OUTN  25

#define LOG2E   1.4426950408889634f
#define M_SIG  (-1.4426950408889634f)   // sigmoid exp2 prescale
#define M_TANH (-2.8853901f)            // tanh exp2 prescale (-2*log2e)

// ---------- helpers ----------
__device__ __forceinline__ float fast_exp2(float x) {
#if __has_builtin(__builtin_amdgcn_exp2f)
  return __builtin_amdgcn_exp2f(x);
#else
  return exp2f(x);
#endif
}

__device__ __forceinline__ float fast_rcp(float x) {
#if __has_builtin(__builtin_amdgcn_rcpf)
  return __builtin_amdgcn_rcpf(x);
#else
  return 1.0f / x;
#endif
}

__device__ __forceinline__ float rl(float v, int lane) {
  return __int_as_float(__builtin_amdgcn_readlane(__float_as_int(v), lane));
}

// broadcast quad-lane K (0..3) to all 4 lanes of each quad via DPP quad_perm
template <int K>
__device__ __forceinline__ float qbcast(float v) {
  return __int_as_float(__builtin_amdgcn_update_dpp(
      0, __float_as_int(v), K * 0x55, 0xF, 0xF, true));
}

// ---------- kernel A ----------
// xw0[t][g] = (x[t,B-1,:]·w_ih0[g,:] + b_ih0[g] + b_hh0[g]) * m(g)
// m(g) = M_TANH for g-gate rows (30..44), else M_SIG  (exp2-domain prescale)
__global__ void precompute_xw0(const float* __restrict__ x,
                               const float* __restrict__ w_ih0,
                               const float* __restrict__ b_ih0,
                               const float* __restrict__ b_hh0,
                               float* __restrict__ xw0) {
  int idx = blockIdx.x * blockDim.x + threadIdx.x;
  if (idx >= T_SEQ * G4) return;
  int t = idx / G4;
  int g = idx - t * G4;
  const float* xp = x + ((size_t)t * BATCH + (BATCH - 1)) * D_IN;
  float a = b_ih0[g] + b_hh0[g];
#pragma unroll
  for (int d = 0; d < D_IN; ++d) a = fmaf(xp[d], w_ih0[g * D_IN + d], a);
  float m = (g / H == 2) ? M_TANH : M_SIG;
  xw0[idx] = a * m;
}

// ---------- kernel B: serial 2-layer LSTM + linear, one wave, stage-skewed ----------
// lane = 4*unit + gate_type ; gate_type in {0:i, 1:f, 2:g(tanh), 3:o}
// Iteration i computes: L0 step i, L1 step i-1, LIN step i-2.  The three
// dependency chains are independent within an iteration, so the scheduler
// interleaves them into the (previously ~83% idle) issue slots.
__global__ void __launch_bounds__(64, 1)
lstm_serial(const float* __restrict__ xw0,
            const float* __restrict__ w_hh0,
            const float* __restrict__ w_ih1,
            const float* __restrict__ w_hh1,
            const float* __restrict__ b_ih1,
            const float* __restrict__ b_hh1,
            const float* __restrict__ w_lin,
            const float* __restrict__ b_lin,
            float* __restrict__ out) {
  const int lane = threadIdx.x;
  const int ty = lane & 3;
  const int j  = lane >> 2;                  // unit 0..15 (15 = idle quad)
  const int g  = (j < H) ? (ty * H + j) : 0; // PyTorch gate row (i,f,g,o blocks)

  const bool  isT = (ty == 2);
  const float m   = isT ? M_TANH : M_SIG;       // pre-activation prescale
  // activation: e=exp2(a'); s=rcp(1+e); v = s*scv + offv
  //   sigmoid rows: v = s
  //   g rows: v = M_TANH * tanh(a)  (c kept in M_TANH-scaled domain)
  const float scv  = isT ? (2.0f * M_TANH) : 1.0f;
  const float offv = isT ? (-M_TANH) : 0.0f;

  // per-lane weight rows (registers), prescaled by m
  float w0[H], wi1[H], wh1[H];
#pragma unroll
  for (int k = 0; k < H; ++k) {
    w0[k]  = w_hh0[g * H + k] * m;
    wi1[k] = w_ih1[g * H + k] * m;
    wh1[k] = w_hh1[g * H + k] * m;
  }
  const float bias1 = (b_ih1[g] + b_hh1[g]) * m;

  // linear weights on lanes 0..24 (unscaled)
  float wl[H];
  {
    int o = (lane < OUTN) ? lane : 0;
#pragma unroll
    for (int k = 0; k < H; ++k) wl[k] = w_lin[o * H + k];
  }
  const float bl = b_lin[(lane < OUTN) ? lane : 0];

  float c0 = 0.0f, c1 = 0.0f;    // cell states, scaled by M_TANH
  float sh0[H], sh1[H];          // wave-uniform broadcasts of h0[t-1], h1[t-2]
#pragma unroll
  for (int k = 0; k < H; ++k) { sh0[k] = 0.0f; sh1[k] = 0.0f; }

  float h0v = 0.0f, h1v = 0.0f;

  // ---- stage bodies ----
  auto L0 = [&](float xw) {
    float a0 = xw, a1 = 0.0f, a2 = 0.0f;
#pragma unroll
    for (int k = 0; k < 5; ++k)   a0 = fmaf(w0[k], sh0[k], a0);
#pragma unroll
    for (int k = 5; k < 10; ++k)  a1 = fmaf(w0[k], sh0[k], a1);
#pragma unroll
    for (int k = 10; k < 15; ++k) a2 = fmaf(w0[k], sh0[k], a2);
    float a = a0 + (a1 + a2);
    float e = fast_exp2(a);
    float s = fast_rcp(1.0f + e);
    float v = fmaf(s, scv, offv);
    float vi = qbcast<0>(v), vf = qbcast<1>(v), vg = qbcast<2>(v), vo = qbcast<3>(v);
    c0 = fmaf(vf, c0, vi * vg);                       // scaled domain
    float th = fmaf(fast_rcp(1.0f + fast_exp2(c0)), 2.0f, -1.0f);
    h0v = vo * th;
  };
  auto L1 = [&]() {
    float u0 = bias1, u1 = 0.0f, u2 = 0.0f, u3 = 0.0f, u4 = 0.0f, u5 = 0.0f;
#pragma unroll
    for (int k = 0; k < 5; ++k)   { u0 = fmaf(wi1[k], sh0[k], u0); u3 = fmaf(wh1[k], sh1[k], u3); }
#pragma unroll
    for (int k = 5; k < 10; ++k)  { u1 = fmaf(wi1[k], sh0[k], u1); u4 = fmaf(wh1[k], sh1[k], u4); }
#pragma unroll
    for (int k = 10; k < 15; ++k) { u2 = fmaf(wi1[k], sh0[k], u2); u5 = fmaf(wh1[k], sh1[k], u5); }
    float b = ((u0 + u1) + (u2 + u3)) + (u4 + u5);
    float e = fast_exp2(b);
    float s = fast_rcp(1.0f + e);
    float v = fmaf(s, scv, offv);
    float qi = qbcast<0>(v), qf = qbcast<1>(v), qg = qbcast<2>(v), qo = qbcast<3>(v);
    c1 = fmaf(qf, c1, qi * qg);
    float th = fmaf(fast_rcp(1.0f + fast_exp2(c1)), 2.0f, -1.0f);
    h1v = qo * th;
  };
  auto B0 = [&]() {
#pragma unroll
    for (int k = 0; k < H; ++k) sh0[k] = rl(h0v, 4 * k);
  };
  auto B1 = [&]() {
#pragma unroll
    for (int k = 0; k < H; ++k) sh1[k] = rl(h1v, 4 * k);
  };
  auto LIN = [&](int t2, bool do_store) {
    float o0 = bl, o1 = 0.0f, o2 = 0.0f;
#pragma unroll
    for (int k = 0; k < 5; ++k)   o0 = fmaf(wl[k], sh1[k], o0);
#pragma unroll
    for (int k = 5; k < 10; ++k)  o1 = fmaf(wl[k], sh1[k], o1);
#pragma unroll
    for (int k = 10; k < 15; ++k) o2 = fmaf(wl[k], sh1[k], o2);
    if (do_store && lane < OUTN) out[t2 * OUTN + lane] = o0 + (o1 + o2);
  };

  // ---- prologue: i = 0 (L0 only) ----
  float xw_cur = xw0[g];            // t = 0
  float xw_n1  = xw0[1 * G4 + g];   // t = 1
  L0(xw_cur);
  B0();
  xw_cur = xw_n1;
  xw_n1  = xw0[2 * G4 + g];

  // ---- main loop: i = 1 .. T-1 ----
  for (int i = 1; i < T_SEQ; ++i) {
    int tn = (i + 2 < T_SEQ) ? (i + 2) : 0;
    float xw_n2 = xw0[tn * G4 + g];

    L1();                    // step i-1 (uses sh0 = h0[i-1], sh1 = h1[i-2])
    L0(xw_cur);              // step i   (uses sh0 = h0[i-1])
    LIN(i - 2, i >= 2);      // step i-2 (uses sh1 = h1[i-2])

    B0();                    // sh0 <- h0[i]
    B1();                    // sh1 <- h1[i-1]

    xw_cur = xw_n1;
    xw_n1  = xw_n2;
  }

  // ---- epilogue ----
  LIN(T_SEQ - 2, true);      // uses sh1 = h1[T-2]
  L1();                      // step T-1 (uses sh0 = h0[T-1])
  B1();
  LIN(T_SEQ - 1, true);
}

// ---------- launch ----------
extern "C" void kernel_launch(void* const* d_in, const int* in_sizes, int n_in,
                              void* d_out, int out_size, void* d_ws, size_t ws_size,
                              hipStream_t stream) {
  const float* x     = (const float*)d_in[0];
  const float* w_ih0 = (const float*)d_in[1];
  const float* w_hh0 = (const float*)d_in[2];
  const float* b_ih0 = (const float*)d_in[3];
  const float* b_hh0 = (const float*)d_in[4];
  const float* w_ih1 = (const float*)d_in[5];
  const float* w_hh1 = (const float*)d_in[6];
  const float* b_ih1 = (const float*)d_in[7];
  const float* b_hh1 = (const float*)d_in[8];
  const float* w_lin = (const float*)d_in[9];
  const float* b_lin = (const float*)d_in[10];
  float* out = (float*)d_out;
  float* xw0 = (float*)d_ws;  // 512*60*4 = 122880 B

  precompute_xw0<<<dim3((T_SEQ * G4 + 255) / 256), dim3(256), 0, stream>>>(
      x, w_ih0, b_ih0, b_hh0, xw0);
  lstm_serial<<<dim3(1), dim3(64), 0, stream>>>(
      xw0, w_hh0, w_ih1, w_hh1, b_ih1, b_hh1, w_lin, b_lin, out);
}